// Round 10
// baseline (98.093 us; speedup 1.0000x reference)
//
#include <hip/hip_runtime.h>
#include <hip/hip_bf16.h>
#include <stdint.h>

#define B_    4
#define N_    4096
#define FIN   64
#define NPROP 64
#define NFILT 128
#define KSEL  40
#define ROWS  (B_ * N_)
#define CAP   160
#define CAPP  176

typedef __attribute__((ext_vector_type(8)))  short short8;
typedef __attribute__((ext_vector_type(4)))  float f32x4;
typedef __attribute__((ext_vector_type(16))) float f32x16;

__device__ __forceinline__ unsigned b16rne(float v) {
    unsigned u = __float_as_uint(v);
    return (u + 0x7FFFu + ((u >> 16) & 1u)) >> 16;
}
__device__ __forceinline__ float fromb16(unsigned h) {
    return __uint_as_float(h << 16);
}
// multiply both packed bf16 halves by -2 (sign flip + exponent+1); exact
__device__ __forceinline__ unsigned neg2pk(unsigned p) {
    return (p + 0x00800080u) ^ 0x80008000u;
}

// ---------------- K0: pack W_out into bf16 hi/lo MFMA-B layout ------------
__global__ __launch_bounds__(192) void k0_packW(
    const float* __restrict__ Wo, unsigned short* __restrict__ Wpk)
{
    int c = blockIdx.x, k = threadIdx.x;
    float wv = Wo[k * NFILT + c];
    unsigned wh = b16rne(wv);
    unsigned wl = b16rne(wv - fromb16(wh));
    Wpk[(size_t)c * 576 + k]       = (unsigned short)wh;
    Wpk[(size_t)c * 576 + 192 + k] = (unsigned short)wh;
    Wpk[(size_t)c * 576 + 384 + k] = (unsigned short)wl;
}

// ---------------- K1: feat projection + bf16 hi/lo MFMA packs -------------
// Bpk[point] (2 x uint4 = 16 bf16):  k0..7 = [h(4), h(4)], k8..15 = [l(4), 1,1, nh, nl]
// A-fragment derived in k2:          k0..7 = [-2h, -2l],   k8..15 = [-2h, nh, nl, 1, 1]
// so  A.B = -2(h.h + l.h + h.l) + n_i + n_j = d^2 + O(1e-5)
__global__ __launch_bounds__(256) void k1_proj(
    const float* __restrict__ x, const float* __restrict__ Wf, const float* __restrict__ bf,
    const float* __restrict__ Ws, const float* __restrict__ bs,
    float* __restrict__ feat, uint4* __restrict__ Bpk)
{
    int wid  = threadIdx.x >> 6;
    int lane = threadIdx.x & 63;
    int row  = blockIdx.x * 4 + wid;

    float xv = x[row * FIN + lane];
    float acc = bf[lane];
    float c0 = bs[0], c1 = bs[1], c2 = bs[2], c3 = bs[3];
    #pragma unroll 16
    for (int k = 0; k < FIN; ++k) {
        float xk = __shfl(xv, k);
        acc += xk * Wf[k * NPROP + lane];
        float4 w4 = reinterpret_cast<const float4*>(Ws)[k];
        c0 += xk * w4.x; c1 += xk * w4.y; c2 += xk * w4.z; c3 += xk * w4.w;
    }
    feat[row * NPROP + lane] = acc;

    unsigned h0 = b16rne(c0), h1 = b16rne(c1), h2 = b16rne(c2), h3 = b16rne(c3);
    unsigned l0 = b16rne(c0 - fromb16(h0)), l1 = b16rne(c1 - fromb16(h1));
    unsigned l2 = b16rne(c2 - fromb16(h2)), l3 = b16rne(c3 - fromb16(h3));
    float n = c0 * c0; n = fmaf(c1, c1, n); n = fmaf(c2, c2, n); n = fmaf(c3, c3, n);
    unsigned nih = b16rne(n), nil = b16rne(n - fromb16(nih));
    unsigned v0 = h0 | (h1 << 16), v1 = h2 | (h3 << 16);
    unsigned v4 = l0 | (l1 << 16), v5 = l2 | (l3 << 16);
    unsigned on2 = 0x3F803F80u, nn = nih | (nil << 16);
    if (lane < 2) {
        uint4 p = lane ? make_uint4(v4, v5, on2, nn) : make_uint4(v0, v1, v0, v1);
        Bpk[row * 2 + lane] = p;
    }
}

// ---------------- K2: 32x32x16-MFMA KNN top-40 + fused output GEMM --------
// Block = 32-query strip, 8 waves x 512 candidates (16 MFMA tiles of 32).
// D layout (m74/m101): col = lane&31, row = (reg&3)+8*(reg>>2)+4*(lane>>5).
// A/B: lane holds 8 bf16 of row/col (lane&31), k-half = lane>>5.
// Pass 1: MFMA + 16 fminf -> col-group merge (shfl_xor 8,16) -> 64 group
//         minima per row (groups of 64 cands); bitonic-64 -> tau.
// Pass 2: re-stream, float-cmp drain, survivors -> LDS. Rank = #smaller.
// P4:     weights from key's 20-bit dist field; epilogue GEMM via MFMA.
__global__ __launch_bounds__(512) void k2_knn(
    const uint4* __restrict__ Bpk, const float* __restrict__ feat,
    const float* __restrict__ x, const unsigned short* __restrict__ Wpk,
    const float* __restrict__ bo, float* __restrict__ out)
{
    __shared__ unsigned minlds[32][68];
    __shared__ unsigned taulds[32];
    __shared__ unsigned survK[32][CAPP];
    __shared__ int      cnt[32];
    __shared__ unsigned winC[32][KSEL];
    __shared__ unsigned short Upk[32][392];   // U hi at f, lo at 192+f

    int tid = threadIdx.x, w = tid >> 6, lane = tid & 63;
    int strip = blockIdx.x & 127;
    int b     = blockIdx.x >> 7;
    int q0    = strip * 32;
    int col = lane & 31, h = lane >> 5;
    int g = lane >> 4, li = lane & 15;        // epilogue indices (16x16x32 D)
    size_t pbase = (size_t)b * N_;

    if (tid < 32) cnt[tid] = 0;

    // A fragment: query q0+col, k-half h
    short8 afr;
    {
        uint4 u0 = Bpk[(pbase + q0 + col) * 2 + 0];
        uint4 u1 = Bpk[(pbase + q0 + col) * 2 + 1];
        union { uint4 u; short8 s; } cv;
        cv.u = (h == 0) ? make_uint4(neg2pk(u0.x), neg2pk(u0.y), neg2pk(u1.x), neg2pk(u1.y))
                        : make_uint4(neg2pk(u0.x), neg2pk(u0.y), u1.w, u1.z);
        afr = cv.s;
    }

    // B stream: candidate cbase + t*32 + col, k-half h; one uint4/lane/tile
    const uint4* bp = Bpk + (pbase + w * 512 + col) * 2 + h;

    // ---- pass 1: MFMA + per-row float minima ----
    float fm[16];
    #pragma unroll
    for (int r = 0; r < 16; ++r) fm[r] = 1e30f;
    uint4 nb = bp[0];
    #pragma unroll 4
    for (int t = 0; t < 16; ++t) {
        union { uint4 u; short8 s; } bv; bv.u = nb;
        if (t < 15) nb = bp[(t + 1) * 64];
        f32x16 d = __builtin_amdgcn_mfma_f32_32x32x16_bf16(afr, bv.s, (f32x16){0.f}, 0, 0, 0);
        #pragma unroll
        for (int r = 0; r < 16; ++r) fm[r] = fminf(fm[r], d[r]);
    }
    // merge col-groups {c, c+8, c+16, c+24} -> 64 groups/row of 64 cands
    #pragma unroll
    for (int r = 0; r < 16; ++r) {
        float v = fm[r];
        v = fminf(v, __shfl_xor(v, 8));
        v = fminf(v, __shfl_xor(v, 16));
        fm[r] = v;
    }
    if ((lane & 24) == 0) {
        #pragma unroll
        for (int r = 0; r < 16; ++r) {
            int row = (r & 3) + 8 * (r >> 2) + 4 * h;
            minlds[row][w * 8 + (lane & 7)] = __float_as_uint(fmaxf(fm[r], 0.0f));
        }
    }
    __syncthreads();

    // ---- tau: bitonic-64 per row (4 rows/wave), take #39 ----
    unsigned sv[4];
    #pragma unroll
    for (int e = 0; e < 4; ++e) sv[e] = minlds[4 * w + e][lane];
    #pragma unroll
    for (int k = 2; k <= 64; k <<= 1) {
        #pragma unroll
        for (int j2 = k >> 1; j2 >= 1; j2 >>= 1) {
            bool up = (((lane & k) == 0) == ((lane & j2) == 0));
            #pragma unroll
            for (int e = 0; e < 4; ++e) {
                unsigned o = (unsigned)__shfl_xor((int)sv[e], j2);
                sv[e] = up ? min(sv[e], o) : max(sv[e], o);
            }
        }
    }
    if (lane == 39) {
        #pragma unroll
        for (int e = 0; e < 4; ++e)
            taulds[4 * w + e] = (sv[e] & 0xFFFFF000u) | 0xFFFu;
    }
    __syncthreads();

    float tauF[16];
    #pragma unroll
    for (int r = 0; r < 16; ++r)
        tauF[r] = __uint_as_float(taulds[(r & 3) + 8 * (r >> 2) + 4 * h]);

    bool selfDiag = (h == ((col >> 2) & 1));
    int  rs       = ((col >> 3) << 2) | (col & 3);
    int  tdiag    = (w == (strip >> 4)) ? (strip & 15) : 99;   // uniform per wave

    // ---- pass 2: re-stream via MFMA, float-cmp drain ----
    nb = bp[0];
    #pragma unroll 2
    for (int t = 0; t < 16; ++t) {
        union { uint4 u; short8 s; } bv; bv.u = nb;
        if (t < 15) nb = bp[(t + 1) * 64];
        f32x16 d = __builtin_amdgcn_mfma_f32_32x32x16_bf16(afr, bv.s, (f32x16){0.f}, 0, 0, 0);
        unsigned idx = (unsigned)((w * 16 + t) * 32 + col);
        if (t == tdiag) {                                      // uniform: diag tile
            #pragma unroll
            for (int r = 0; r < 16; ++r) {
                int rowc = (r & 3) + 8 * (r >> 2) + 4 * h;
                if (selfDiag && r == rs) {                     // self -> rank 0
                    int s = atomicAdd(&cnt[rowc], 1); if (s < CAP) survK[rowc][s] = 0u;
                } else if (d[r] <= tauF[r]) {
                    unsigned c = (__float_as_uint(fmaxf(d[r], 0.f)) & 0xFFFFF000u) | idx;
                    int s = atomicAdd(&cnt[rowc], 1); if (s < CAP) survK[rowc][s] = c;
                }
            }
        } else {
            #pragma unroll
            for (int r = 0; r < 16; ++r) {
                if (d[r] <= tauF[r]) {
                    int rowc = (r & 3) + 8 * (r >> 2) + 4 * h;
                    unsigned c = (__float_as_uint(fmaxf(d[r], 0.f)) & 0xFFFFF000u) | idx;
                    int s = atomicAdd(&cnt[rowc], 1); if (s < CAP) survK[rowc][s] = c;
                }
            }
        }
    }
    __syncthreads();

    // ---- rank survivors; ranks 1..39 -> winners (4 rows per wave) ----
    #pragma unroll
    for (int e = 0; e < 4; ++e) {
        int r = 4 * w + e;
        int S = min(cnt[r], CAP);
        if (lane < 16) survK[r][S + lane] = 0xFFFFFFFFu;       // sentinels
        for (int rr = lane; rr < S; rr += 64) {
            unsigned my = survK[r][rr];
            int c = 0;
            int S4 = (S + 3) >> 2;
            for (int s4 = 0; s4 < S4; ++s4) {
                uint4 u4 = *reinterpret_cast<const uint4*>(&survK[r][4 * s4]);
                c += (u4.x < my) + (u4.y < my) + (u4.z < my) + (u4.w < my);
            }
            if (c >= 1 && c < KSEL) winC[r][c - 1] = my;
        }
    }
    __syncthreads();

    // ---- P4: aggregate 39 winners; pack U = [x | max | mean] hi/lo ----
    const float* fb = feat + pbase * NPROP + lane;
    #pragma unroll 1
    for (int e = 0; e < 4; ++e) {
        int r = 4 * w + e;
        int qi = q0 + r;
        float mx = -3.4e38f, sm = 0.f;
        #pragma unroll 4
        for (int u = 0; u < KSEL / 4; ++u) {
            uint4 cv4 = *reinterpret_cast<const uint4*>(&winC[r][4 * u]);
            #pragma unroll
            for (int e2 = 0; e2 < 4; ++e2) {
                if (4 * u + e2 > KSEL - 2) break;              // compile-time tail skip
                unsigned comp = (e2 == 0) ? cv4.x : (e2 == 1) ? cv4.y : (e2 == 2) ? cv4.z : cv4.w;
                int j = (int)(comp & 0xFFFu);
                float dd = __uint_as_float(comp & 0xFFFFF000u);
                float wt = __expf(-10.f * dd);
                float f  = fb[(size_t)j * NPROP];
                float wf = wt * f;
                mx = fmaxf(mx, wf);
                sm += wf;
            }
        }
        float mean = sm * (1.0f / 39.0f);
        unsigned mh = b16rne(mx),   ml = b16rne(mx - fromb16(mh));
        unsigned eh = b16rne(mean), el = b16rne(mean - fromb16(eh));
        float xv = x[(pbase + qi) * FIN + lane];
        unsigned xh = b16rne(xv),   xl = b16rne(xv - fromb16(xh));
        Upk[r][lane]       = (unsigned short)xh;
        Upk[r][192 + lane] = (unsigned short)xl;
        Upk[r][64 + lane]  = (unsigned short)mh;
        Upk[r][256 + lane] = (unsigned short)ml;
        Upk[r][128 + lane] = (unsigned short)eh;
        Upk[r][320 + lane] = (unsigned short)el;
    }
    __syncthreads();

    // ---- epilogue: out[32 x 128] = U @ W_out + b_out (two 16-row halves) --
    {
        int colc = w * 16 + li;
        const unsigned short* wp = Wpk + (size_t)colc * 576;
        f32x4 o0 = {0.f, 0.f, 0.f, 0.f}, o1 = {0.f, 0.f, 0.f, 0.f};
        #pragma unroll
        for (int s = 0; s < 18; ++s) {
            int koff = (s < 6)  ? (32 * s + 8 * g)
                     : (s < 12) ? (192 + 32 * (s - 6) + 8 * g)
                                : (32 * (s - 12) + 8 * g);
            union { uint4 u; short8 s8; } a0, a1, bv;
            a0.u = *reinterpret_cast<const uint4*>(&Upk[li][koff]);
            a1.u = *reinterpret_cast<const uint4*>(&Upk[16 + li][koff]);
            bv.u = *reinterpret_cast<const uint4*>(&wp[32 * s + 8 * g]);
            o0 = __builtin_amdgcn_mfma_f32_16x16x32_bf16(a0.s8, bv.s8, o0, 0, 0, 0);
            o1 = __builtin_amdgcn_mfma_f32_16x16x32_bf16(a1.s8, bv.s8, o1, 0, 0, 0);
        }
        float bb = bo[colc];
        #pragma unroll
        for (int e = 0; e < 4; ++e) {
            int orow = g * 4 + e;
            out[(size_t)(pbase + q0 + orow) * NFILT + colc]      = o0[e] + bb;
            out[(size_t)(pbase + q0 + 16 + orow) * NFILT + colc] = o1[e] + bb;
        }
    }
}

extern "C" void kernel_launch(void* const* d_in, const int* in_sizes, int n_in,
                              void* d_out, int out_size, void* d_ws, size_t ws_size,
                              hipStream_t stream)
{
    const float* x  = (const float*)d_in[0];
    const float* Wf = (const float*)d_in[1];
    const float* bf = (const float*)d_in[2];
    const float* Ws = (const float*)d_in[3];
    const float* bs = (const float*)d_in[4];
    const float* Wo = (const float*)d_in[5];
    const float* bo = (const float*)d_in[6];
    float* out = (float*)d_out;

    float*          feat = (float*)d_ws;                                       // 4 MB
    uint4*          Bpk  = (uint4*)((char*)d_ws + (size_t)ROWS * NPROP * 4);   // 512 KB
    unsigned short* Wpk  = (unsigned short*)((char*)d_ws
                             + (size_t)ROWS * NPROP * 4 + (size_t)ROWS * 32);  // 144 KB

    k0_packW<<<NFILT, 192, 0, stream>>>(Wo, Wpk);
    k1_proj <<<ROWS / 4, 256, 0, stream>>>(x, Wf, bf, Ws, bs, feat, Bpk);
    k2_knn  <<<B_ * 128, 512, 0, stream>>>(Bpk, feat, x, Wpk, bo, out);
}